// Round 3
// baseline (130.573 us; speedup 1.0000x reference)
//
#include <hip/hip_runtime.h>
#include <hip/hip_bf16.h>

// out = (4096 * (x @ Wv)) @ w_proj + b_proj   [softmax rows sum to 1 =>
// head_w == N_NODES exactly; adj, w_q, w_k never affect the output]
// Wv[d][c=h*128+hd] = w_qkv[2][h][d][hd].  All global tensors fp32.
//
// R8: two dispatches. build_Mt unchanged (R5-proven). gemm_out re-tiled for
// occupancy: 64x64 block tile (wave tile 32x32), grid 8x64 = 512 blocks ->
// 2 blocks/CU = 2 waves/SIMD (R7 had 1 wave/SIMD; its in-reg fp32->bf16 cvt
// doubled the loads per K-iter and the exposed latency had no TLP to hide
// under). Same load:MFMA ratio, half the VGPR pressure, 2x TLP.
// Numerics identical to R5/R7 (same K-order, same bf16 rounding).
// Fixed ~110us of harness poison/restore + ~15 small dispatches is the floor.

constexpr int NNODES = 4096;
constexpr int DIM = 512;

typedef __bf16 bf16x8 __attribute__((ext_vector_type(8)));
typedef float f32x4 __attribute__((ext_vector_type(4)));

__device__ __forceinline__ bf16x8 cvt8(const float* p) {
  const f32x4 lo = *(const f32x4*)p;
  const f32x4 hi = *(const f32x4*)(p + 4);
  bf16x8 r;
#pragma unroll
  for (int j = 0; j < 4; ++j) { r[j] = (__bf16)lo[j]; r[4 + j] = (__bf16)hi[j]; }
  return r;
}

// ---------------------------------------------------------------------------
// Kernel 1: Mt[o][d] = 4096 * sum_c Wp[c][o] * Wv[d][c], bf16.
// One wave per 32(o) x 32(d) tile. Grid 16x16 = 256 single-wave blocks.
// ---------------------------------------------------------------------------
__global__ __launch_bounds__(64) void build_Mt(
    const float* __restrict__ w_qkv,
    const float* __restrict__ w_proj,
    __bf16* __restrict__ Mt) {
  const int lane = threadIdx.x;
  const int ln = lane & 15, q = lane >> 4;
  const int m0 = blockIdx.y * 32;   // o rows of Mt
  const int n0 = blockIdx.x * 32;   // d cols of Mt
  const float* __restrict__ wv = w_qkv + 2 * 4 * DIM * 128;  // v slice

  f32x4 acc[2][2] = {};

#pragma unroll
  for (int k0 = 0; k0 < DIM; k0 += 32) {   // k = c (h*128+hd)
    const int h = k0 >> 7, hb = k0 & 127;
    bf16x8 af[2], bf[2];
#pragma unroll
    for (int mi = 0; mi < 2; ++mi) {
      float raw[8];
#pragma unroll
      for (int j = 0; j < 8; ++j)
        raw[j] = w_proj[(k0 + q * 8 + j) * DIM + (m0 + mi * 16 + ln)];
#pragma unroll
      for (int j = 0; j < 8; ++j) af[mi][j] = (__bf16)raw[j];
    }
#pragma unroll
    for (int ni = 0; ni < 2; ++ni)
      bf[ni] = cvt8(&wv[((size_t)h * DIM + (n0 + ni * 16 + ln)) * 128 + hb + q * 8]);
#pragma unroll
    for (int mi = 0; mi < 2; ++mi)
#pragma unroll
      for (int ni = 0; ni < 2; ++ni)
        acc[mi][ni] = __builtin_amdgcn_mfma_f32_16x16x32_bf16(
            af[mi], bf[ni], acc[mi][ni], 0, 0, 0);
  }

#pragma unroll
  for (int mi = 0; mi < 2; ++mi)
#pragma unroll
    for (int ni = 0; ni < 2; ++ni)
#pragma unroll
      for (int r = 0; r < 4; ++r) {
        const int o = m0 + mi * 16 + q * 4 + r;
        const int d = n0 + ni * 16 + ln;
        Mt[o * DIM + d] = (__bf16)(acc[mi][ni][r] * (float)NNODES);
      }
}

// ---------------------------------------------------------------------------
// Kernel 2: out[b][o] = sum_d (bf16)x[b][d] * Mt[o][d] + bias[o], fp32 out.
// 256 threads = 4 waves (2m x 2n); wave tile 32(b) x 32(o); block 64x64.
// Grid (512/64) x (4096/64) = 8 x 64 = 512 blocks -> 2 blocks/CU,
// 2 waves/SIMD (vs R7's 1). A-frags cvt'd fp32->bf16 in-register.
// ---------------------------------------------------------------------------
__global__ __launch_bounds__(256) void gemm_out(
    const float* __restrict__ x,
    const __bf16* __restrict__ Mt,
    const float* __restrict__ bias,
    float* __restrict__ out) {
  const int tid = threadIdx.x;
  const int wave = tid >> 6, lane = tid & 63;
  const int ln = lane & 15, q = lane >> 4;
  const int m0 = blockIdx.y * 64 + (wave >> 1) * 32;   // b rows
  const int n0 = blockIdx.x * 64 + (wave & 1) * 32;    // o cols

  f32x4 acc[2][2] = {};

#pragma unroll 4
  for (int k0 = 0; k0 < DIM; k0 += 32) {
    bf16x8 af[2], bf[2];
#pragma unroll
    for (int mi = 0; mi < 2; ++mi)
      af[mi] = cvt8(&x[(size_t)(m0 + mi * 16 + ln) * DIM + k0 + q * 8]);
#pragma unroll
    for (int ni = 0; ni < 2; ++ni)
      bf[ni] = *(const bf16x8*)&Mt[(size_t)(n0 + ni * 16 + ln) * DIM + k0 + q * 8];
#pragma unroll
    for (int mi = 0; mi < 2; ++mi)
#pragma unroll
      for (int ni = 0; ni < 2; ++ni)
        acc[mi][ni] = __builtin_amdgcn_mfma_f32_16x16x32_bf16(
            af[mi], bf[ni], acc[mi][ni], 0, 0, 0);
  }

#pragma unroll
  for (int ni = 0; ni < 2; ++ni) {
    const int o = n0 + ni * 16 + ln;
    const float bj = bias[o];
#pragma unroll
    for (int mi = 0; mi < 2; ++mi)
#pragma unroll
      for (int r = 0; r < 4; ++r) {
        const int b = m0 + mi * 16 + q * 4 + r;
        out[(size_t)b * DIM + o] = acc[mi][ni][r] + bj;
      }
  }
}

extern "C" void kernel_launch(void* const* d_in, const int* in_sizes, int n_in,
                              void* d_out, int out_size, void* d_ws, size_t ws_size,
                              hipStream_t stream) {
  const float* x      = (const float*)d_in[0];
  // d_in[1] = adj — irrelevant (softmax rows sum to 1), never read
  const float* w_qkv  = (const float*)d_in[2];
  const float* w_proj = (const float*)d_in[3];
  const float* b_proj = (const float*)d_in[4];
  __bf16* Mt = (__bf16*)d_ws;                          // 512 KB
  float* out = (float*)d_out;                          // 4096*512 fp32

  build_Mt<<<dim3(DIM / 32, DIM / 32), 64, 0, stream>>>(w_qkv, w_proj, Mt);
  gemm_out<<<dim3(DIM / 64, NNODES / 64), 256, 0, stream>>>(x, Mt, b_proj, out);
}

// Round 4
// 120.279 us; speedup vs baseline: 1.0856x; 1.0856x over previous
//
#include <hip/hip_runtime.h>
#include <hip/hip_bf16.h>

// out = (4096 * (x @ Wv)) @ w_proj + b_proj   [softmax rows sum to 1 =>
// head_w == N_NODES exactly; adj, w_q, w_k never affect the output]
// Wv[d][c=h*128+hd] = w_qkv[2][h][d][hd].  All global tensors fp32.
//
// R9: R0's proven components, 3 dispatches -> 2 by merging the two
// INDEPENDENT prep steps (no added sync):
//  1) prep: every thread cvts one bf16x8 of x -> xb (R0's cvt_x slice);
//     wave 0 of each of the 1024 blocks additionally builds one 16x16 tile
//     of Mt[o][d] = 4096 * (Wv@Wp)^T (same K-order/MFMA chain per element
//     as R5's 32x32 tiles -> bit-identical; validated in R6 phase 1b).
//  2) gemm_out: R0's byte-for-byte gemm (xb bf16 A-frags as single 16B
//     loads, 64x128 block tile, 4 waves). In-reg-cvt variants (R7/R8)
//     measured ~4us slower; reverted.
// Fixed ~110us of harness poison/restore fills is the floor (all top-5
// dispatches are 41us 256MB fillBuffer at 81-84% HBM peak).

constexpr int NNODES = 4096;
constexpr int DIM = 512;

typedef __bf16 bf16x8 __attribute__((ext_vector_type(8)));
typedef float f32x4 __attribute__((ext_vector_type(4)));

__device__ __forceinline__ bf16x8 cvt8(const float* p) {
  const f32x4 lo = *(const f32x4*)p;
  const f32x4 hi = *(const f32x4*)(p + 4);
  bf16x8 r;
#pragma unroll
  for (int j = 0; j < 4; ++j) { r[j] = (__bf16)lo[j]; r[4 + j] = (__bf16)hi[j]; }
  return r;
}

// ---------------------------------------------------------------------------
// Kernel 1: prep. Grid 1024 x 256.
//  - all threads: xb = (bf16)x, 8 elems each (1024*256*8 = 4096*512).
//  - wave 0 per block: one 16x16 Mt tile; bid -> (o0, d0) over a 32x32
//    tile grid. Waves 1-3 exit after the cvt (balanced enough at 4 blk/CU).
// ---------------------------------------------------------------------------
__global__ __launch_bounds__(256) void prep(
    const float* __restrict__ x,
    const float* __restrict__ w_qkv,
    const float* __restrict__ w_proj,
    __bf16* __restrict__ xb,
    __bf16* __restrict__ Mt) {
  const int tid = threadIdx.x;
  const int bid = blockIdx.x;

  // ---- cvt slice (identical to R0 cvt_x) ----
  {
    const size_t i8 = ((size_t)bid * 256 + tid) * 8;
    *(bf16x8*)&xb[i8] = cvt8(&x[i8]);
  }

  // ---- Mt tile (wave 0 only): Mt[o][d] = 4096 * sum_c Wp[c][o]*Wv[d][c] ----
  if (tid < 64) {
    const int lane = tid;
    const int ln = lane & 15, q = lane >> 4;
    const int o0 = (bid >> 5) * 16;            // o rows of Mt
    const int d0 = (bid & 31) * 16;            // d cols of Mt
    const float* __restrict__ wv = w_qkv + 2 * 4 * DIM * 128;  // v slice

    f32x4 acc = {};
#pragma unroll
    for (int k0 = 0; k0 < DIM; k0 += 32) {     // k = c (h*128+hd)
      const int h = k0 >> 7, hb = k0 & 127;
      float raw[8];
#pragma unroll
      for (int j = 0; j < 8; ++j)
        raw[j] = w_proj[(k0 + q * 8 + j) * DIM + o0 + ln];
      bf16x8 af, bf;
#pragma unroll
      for (int j = 0; j < 8; ++j) af[j] = (__bf16)raw[j];
      bf = cvt8(&wv[((size_t)h * DIM + d0 + ln) * 128 + hb + q * 8]);
      acc = __builtin_amdgcn_mfma_f32_16x16x32_bf16(af, bf, acc, 0, 0, 0);
    }
#pragma unroll
    for (int r = 0; r < 4; ++r)
      Mt[(o0 + q * 4 + r) * DIM + d0 + ln] = (__bf16)(acc[r] * (float)NNODES);
  }
}

// ---------------------------------------------------------------------------
// Kernel 2: out[b][o] = sum_d xb[b][d] * Mt[o][d] + bias[o], fp32 out.
// 256 threads = 4 waves (2m x 2n); wave tile 32(b) x 64(o); block 64x128.
// Grid (512/128) x (4096/64) = 4 x 64 = 256 blocks.
// Per wave K-iter: 2 + 4 = 6 x 16B loads, 8 MFMAs, zero cvt.  (R0 proven.)
// ---------------------------------------------------------------------------
__global__ __launch_bounds__(256) void gemm_out(
    const __bf16* __restrict__ xb,
    const __bf16* __restrict__ Mt,
    const float* __restrict__ bias,
    float* __restrict__ out) {
  const int tid = threadIdx.x;
  const int wave = tid >> 6, lane = tid & 63;
  const int ln = lane & 15, q = lane >> 4;
  const int m0 = blockIdx.y * 64 + (wave >> 1) * 32;   // b rows
  const int n0 = blockIdx.x * 128 + (wave & 1) * 64;   // o cols

  f32x4 acc[2][4] = {};

#pragma unroll 4
  for (int k0 = 0; k0 < DIM; k0 += 32) {
    bf16x8 af[2], bf[4];
#pragma unroll
    for (int mi = 0; mi < 2; ++mi)
      af[mi] = *(const bf16x8*)&xb[(size_t)(m0 + mi * 16 + ln) * DIM + k0 + q * 8];
#pragma unroll
    for (int ni = 0; ni < 4; ++ni)
      bf[ni] = *(const bf16x8*)&Mt[(size_t)(n0 + ni * 16 + ln) * DIM + k0 + q * 8];
#pragma unroll
    for (int mi = 0; mi < 2; ++mi)
#pragma unroll
      for (int ni = 0; ni < 4; ++ni)
        acc[mi][ni] = __builtin_amdgcn_mfma_f32_16x16x32_bf16(
            af[mi], bf[ni], acc[mi][ni], 0, 0, 0);
  }

#pragma unroll
  for (int ni = 0; ni < 4; ++ni) {
    const int o = n0 + ni * 16 + ln;
    const float bj = bias[o];
#pragma unroll
    for (int mi = 0; mi < 2; ++mi)
#pragma unroll
      for (int r = 0; r < 4; ++r) {
        const int b = m0 + mi * 16 + q * 4 + r;
        out[(size_t)b * DIM + o] = acc[mi][ni][r] + bj;
      }
  }
}

extern "C" void kernel_launch(void* const* d_in, const int* in_sizes, int n_in,
                              void* d_out, int out_size, void* d_ws, size_t ws_size,
                              hipStream_t stream) {
  const float* x      = (const float*)d_in[0];
  // d_in[1] = adj — irrelevant (softmax rows sum to 1), never read
  const float* w_qkv  = (const float*)d_in[2];
  const float* w_proj = (const float*)d_in[3];
  const float* b_proj = (const float*)d_in[4];
  __bf16* Mt = (__bf16*)d_ws;                          // 512 KB
  __bf16* xb = (__bf16*)((char*)d_ws + DIM * DIM * 2); // 4 MB, 16B-aligned
  float* out = (float*)d_out;                          // 4096*512 fp32

  prep<<<dim3(NNODES * DIM / (256 * 8)), 256, 0, stream>>>(x, w_qkv, w_proj, xb, Mt);
  gemm_out<<<dim3(DIM / 128, NNODES / 64), 256, 0, stream>>>(xb, Mt, b_proj, out);
}

// Round 5
// 119.506 us; speedup vs baseline: 1.0926x; 1.0065x over previous
//
#include <hip/hip_runtime.h>
#include <hip/hip_bf16.h>

// out = (4096 * (x @ Wv)) @ w_proj + b_proj   [softmax rows sum to 1 =>
// head_w == N_NODES exactly; adj, w_q, w_k never affect the output]
// Wv[d][c=h*128+hd] = w_qkv[2][h][d][hd].  All global tensors fp32.
//
// R10: R9's 2-dispatch structure (prep merges cvt_x + build_Mt, proven
// -5.1us) + gemm_out latency fixes:
//  - __launch_bounds__(256,1): grid 256 = 1 block/CU = 1 wave/SIMD anyway,
//    so let the compiler use the full VGPR file for deeper load pipelining
//    (was capped at 112 VGPR for occupancy we can't reach).
//  - unroll 8 on the K-loop: more loads in flight per scheduling window.
//  - XCD-chunked block swizzle: flat grid 256, chunk=P%8 -> each XCD's 32
//    blocks cover a contiguous by-range (512KB xb + 512KB Mt fit its L2);
//    round-robin had the 4 blocks sharing xb rows on 4 different XCDs.
// Numerics identical (same per-element FP order). absmax 8.0.
// Fixed ~110us harness poison/restore fill floor (top-5 all 41us 256MB
// fillBuffer at 81-84% HBM peak).

constexpr int NNODES = 4096;
constexpr int DIM = 512;

typedef __bf16 bf16x8 __attribute__((ext_vector_type(8)));
typedef float f32x4 __attribute__((ext_vector_type(4)));

__device__ __forceinline__ bf16x8 cvt8(const float* p) {
  const f32x4 lo = *(const f32x4*)p;
  const f32x4 hi = *(const f32x4*)(p + 4);
  bf16x8 r;
#pragma unroll
  for (int j = 0; j < 4; ++j) { r[j] = (__bf16)lo[j]; r[4 + j] = (__bf16)hi[j]; }
  return r;
}

// ---------------------------------------------------------------------------
// Kernel 1: prep. Grid 1024 x 256.
//  - all threads: xb = (bf16)x, 8 elems each (1024*256*8 = 4096*512).
//  - wave 0 per block: one 16x16 Mt tile; bid -> (o0, d0) over a 32x32
//    tile grid. Waves 1-3 exit after the cvt (4 blocks/CU keeps SIMDs fed).
// ---------------------------------------------------------------------------
__global__ __launch_bounds__(256) void prep(
    const float* __restrict__ x,
    const float* __restrict__ w_qkv,
    const float* __restrict__ w_proj,
    __bf16* __restrict__ xb,
    __bf16* __restrict__ Mt) {
  const int tid = threadIdx.x;
  const int bid = blockIdx.x;

  // ---- cvt slice (identical to R0 cvt_x) ----
  {
    const size_t i8 = ((size_t)bid * 256 + tid) * 8;
    *(bf16x8*)&xb[i8] = cvt8(&x[i8]);
  }

  // ---- Mt tile (wave 0 only): Mt[o][d] = 4096 * sum_c Wp[c][o]*Wv[d][c] ----
  if (tid < 64) {
    const int lane = tid;
    const int ln = lane & 15, q = lane >> 4;
    const int o0 = (bid >> 5) * 16;            // o rows of Mt
    const int d0 = (bid & 31) * 16;            // d cols of Mt
    const float* __restrict__ wv = w_qkv + 2 * 4 * DIM * 128;  // v slice

    f32x4 acc = {};
#pragma unroll
    for (int k0 = 0; k0 < DIM; k0 += 32) {     // k = c (h*128+hd)
      const int h = k0 >> 7, hb = k0 & 127;
      float raw[8];
#pragma unroll
      for (int j = 0; j < 8; ++j)
        raw[j] = w_proj[(k0 + q * 8 + j) * DIM + o0 + ln];
      bf16x8 af, bf;
#pragma unroll
      for (int j = 0; j < 8; ++j) af[j] = (__bf16)raw[j];
      bf = cvt8(&wv[((size_t)h * DIM + d0 + ln) * 128 + hb + q * 8]);
      acc = __builtin_amdgcn_mfma_f32_16x16x32_bf16(af, bf, acc, 0, 0, 0);
    }
#pragma unroll
    for (int r = 0; r < 4; ++r)
      Mt[(o0 + q * 4 + r) * DIM + d0 + ln] = (__bf16)(acc[r] * (float)NNODES);
  }
}

// ---------------------------------------------------------------------------
// Kernel 2: out[b][o] = sum_d xb[b][d] * Mt[o][d] + bias[o], fp32 out.
// 256 threads = 4 waves (2m x 2n); wave tile 32(b) x 64(o); block 64x128.
// Flat grid 256; XCD-chunked swizzle: P -> L = (P%8)*32 + P/8 so each XCD
// owns a contiguous by-range (its 512KB xb slice + 512KB Mt stay in L2).
// Per wave K-iter: 6 x 16B loads, 8 MFMAs, zero cvt.
// ---------------------------------------------------------------------------
__global__ __launch_bounds__(256, 1) void gemm_out(
    const __bf16* __restrict__ xb,
    const __bf16* __restrict__ Mt,
    const float* __restrict__ bias,
    float* __restrict__ out) {
  const int tid = threadIdx.x;
  const int wave = tid >> 6, lane = tid & 63;
  const int ln = lane & 15, q = lane >> 4;

  // XCD-chunked swizzle (256 = 8 XCDs x 32 blocks, bijective).
  const int P = blockIdx.x;
  const int L = (P & 7) * 32 + (P >> 3);
  const int by = L >> 2, bx = L & 3;
  const int m0 = by * 64 + (wave >> 1) * 32;    // b rows
  const int n0 = bx * 128 + (wave & 1) * 64;    // o cols

  f32x4 acc[2][4] = {};

#pragma unroll 8
  for (int k0 = 0; k0 < DIM; k0 += 32) {
    bf16x8 af[2], bf[4];
#pragma unroll
    for (int mi = 0; mi < 2; ++mi)
      af[mi] = *(const bf16x8*)&xb[(size_t)(m0 + mi * 16 + ln) * DIM + k0 + q * 8];
#pragma unroll
    for (int ni = 0; ni < 4; ++ni)
      bf[ni] = *(const bf16x8*)&Mt[(size_t)(n0 + ni * 16 + ln) * DIM + k0 + q * 8];
#pragma unroll
    for (int mi = 0; mi < 2; ++mi)
#pragma unroll
      for (int ni = 0; ni < 4; ++ni)
        acc[mi][ni] = __builtin_amdgcn_mfma_f32_16x16x32_bf16(
            af[mi], bf[ni], acc[mi][ni], 0, 0, 0);
  }

#pragma unroll
  for (int ni = 0; ni < 4; ++ni) {
    const int o = n0 + ni * 16 + ln;
    const float bj = bias[o];
#pragma unroll
    for (int mi = 0; mi < 2; ++mi)
#pragma unroll
      for (int r = 0; r < 4; ++r) {
        const int b = m0 + mi * 16 + q * 4 + r;
        out[(size_t)b * DIM + o] = acc[mi][ni][r] + bj;
      }
  }
}

extern "C" void kernel_launch(void* const* d_in, const int* in_sizes, int n_in,
                              void* d_out, int out_size, void* d_ws, size_t ws_size,
                              hipStream_t stream) {
  const float* x      = (const float*)d_in[0];
  // d_in[1] = adj — irrelevant (softmax rows sum to 1), never read
  const float* w_qkv  = (const float*)d_in[2];
  const float* w_proj = (const float*)d_in[3];
  const float* b_proj = (const float*)d_in[4];
  __bf16* Mt = (__bf16*)d_ws;                          // 512 KB
  __bf16* xb = (__bf16*)((char*)d_ws + DIM * DIM * 2); // 4 MB, 16B-aligned
  float* out = (float*)d_out;                          // 4096*512 fp32

  prep<<<dim3(NNODES * DIM / (256 * 8)), 256, 0, stream>>>(x, w_qkv, w_proj, xb, Mt);
  gemm_out<<<dim3(256), 256, 0, stream>>>(xb, Mt, b_proj, out);
}